// Round 13
// baseline (105.081 us; speedup 1.0000x reference)
//
#include <hip/hip_runtime.h>
#include <stdint.h>

#define N_IMG 32
#define P_TOT 8400
#define NCLS 80
#define NMS_PRE 1000
#define MAXOUT 100
#define SCORE_THRF 0.01f
#define NMS_THRF 0.65f
#define CAND_N 2048
#define NB 512          // histogram bins over dk>>17
#define BINBASE 8192    // valid masked scores [0.01,1.0] -> dk>>17 in [8255,8686]
#define TIE_EPS 0.05f   // sigmoid float-rounding tie window (validated R9/R10/R12, absmax 0)
#define CHUNKS 5        // class chunks of 16
#define TILES 9         // ceil(8400/1024) anchor tiles per image

// Level layout: p in [0,6400): 80x80 s=8 ; [6400,8000): 40x40 s=16 ; [8000,8400): 20x20 s=32

__device__ __forceinline__ float sigmoidf_(float x) { return 1.0f / (1.0f + expf(-x)); }
__device__ __forceinline__ uint32_t ordmap_(uint32_t u) {
    return (u & 0x80000000u) ? ~u : (u | 0x80000000u);   // float bits -> ascending uint
}
__device__ __forceinline__ float unord_(uint32_t o) {    // inverse of ordmap_
    return __uint_as_float((o & 0x80000000u) ? (o ^ 0x80000000u) : ~o);
}
__device__ __forceinline__ void merge2_(uint64_t& a1, uint64_t& a2, uint64_t b1, uint64_t b2) {
    uint64_t lo = a1 < b1 ? a1 : b1;
    a1 = a1 > b1 ? a1 : b1;
    uint64_t m2 = a2 > b2 ? a2 : b2;
    a2 = lo > m2 ? lo : m2;                               // 2nd-largest of the union
}

// ---------------- Kernel 1a: per-chunk packed top-2 logits, per-wave SEQUENTIAL streams ----------
// Block = 1024 thr = 16 waves; covers (image n, 1024-anchor tile, class chunk of 16).
// Wave w walks class (16*ch + w)'s row with float4 loads: 1 KB/wave/instr, consecutive
// iterations consecutive addresses (m13 streaming pattern). LDS transpose, then threads
// 0..255 reduce 16 classes -> packed (logit_ord<<8 | 79-c) top1/top2 per anchor.
__global__ __launch_bounds__(1024) void k_pmax(
    const float* __restrict__ cls0, const float* __restrict__ cls1, const float* __restrict__ cls2,
    ulonglong2* __restrict__ part)
{
    __shared__ float stage[16][256];
    int bid = blockIdx.x;
    int n = bid / (TILES * CHUNKS);
    int r = bid - n * (TILES * CHUNKS);
    int tile = r / CHUNKS, ch = r - tile * CHUNKS;
    int wid = threadIdx.x >> 6, lane = threadIdx.x & 63;
    int cls = ch * 16 + wid;

    for (int seg = 0; seg < 4; ++seg) {
        int abase = tile * 1024 + seg * 256;
        int p0 = abase + lane * 4;              // multiple of 4; level bounds 6400/8000 are too
        if (p0 < P_TOT) {
            const float* cl; int HW, q0;
            if (p0 < 6400)      { cl = cls0; HW = 6400; q0 = p0; }
            else if (p0 < 8000) { cl = cls1; HW = 1600; q0 = p0 - 6400; }
            else                { cl = cls2; HW = 400;  q0 = p0 - 8000; }
            float4 v = *reinterpret_cast<const float4*>(
                cl + (size_t)n * NCLS * HW + (size_t)cls * HW + q0);
            *reinterpret_cast<float4*>(&stage[wid][lane * 4]) = v;
        }
        __syncthreads();
        if (threadIdx.x < 256) {
            int a = threadIdx.x;
            int p = abase + a;
            if (p < P_TOT) {
                uint64_t t1 = 0, t2 = 0;
                #pragma unroll
                for (int k = 0; k < 16; ++k) {
                    uint32_t ord = ordmap_(__float_as_uint(stage[k][a]));
                    uint64_t pk = ((uint64_t)ord << 8) | (uint32_t)(79 - (ch * 16 + k));
                    uint64_t lo = t1 < pk ? t1 : pk;
                    t1 = t1 > pk ? t1 : pk;
                    t2 = t2 > lo ? t2 : lo;
                }
                part[(size_t)ch * (N_IMG * P_TOT) + (size_t)n * P_TOT + p] =
                    make_ulonglong2(t1, t2);
            }
        }
        __syncthreads();
    }
}

// ---------------- Kernel 1b: merge 5 chunk partials -> exact keys ----------------
__global__ __launch_bounds__(256) void k_merge(
    const ulonglong2* __restrict__ part,
    const float* __restrict__ cls0, const float* __restrict__ cls1, const float* __restrict__ cls2,
    const float* __restrict__ obj0, const float* __restrict__ obj1, const float* __restrict__ obj2,
    uint64_t* __restrict__ keys)
{
    int a = blockIdx.x * 256 + threadIdx.x;
    if (a >= N_IMG * P_TOT) return;
    int n = a / P_TOT, p = a - n * P_TOT;

    uint64_t t1 = 0, t2 = 0;
    #pragma unroll
    for (int c = 0; c < CHUNKS; ++c) {
        ulonglong2 v = part[(size_t)c * (N_IMG * P_TOT) + a];
        merge2_(t1, t2, v.x, v.y);
    }
    float l1 = unord_((uint32_t)(t1 >> 8));
    float l2 = unord_((uint32_t)(t2 >> 8));

    const float* cl; const float* ob; int HW, q;
    if (p < 6400)      { cl = cls0; ob = obj0; HW = 6400; q = p; }
    else if (p < 8000) { cl = cls1; ob = obj1; HW = 1600; q = p - 6400; }
    else               { cl = cls2; ob = obj2; HW = 400;  q = p - 8000; }

    float best; int bc;
    if (l2 < l1 - TIE_EPS) {
        // no sigmoid-rounding tie possible: label = top1's class, value by monotonicity
        best = sigmoidf_(l1);
        bc = 79 - (int)(t1 & 0xFFu);
    } else {
        // rare exact path: full sigmoid argmax, first-wins (= jnp.argmax over sigmoids)
        const float* cbase = cl + (size_t)n * NCLS * HW + q;
        uint64_t m = 0;
        #pragma unroll 8
        for (int c = 0; c < NCLS; ++c) {
            float s = sigmoidf_(cbase[(size_t)c * HW]);
            uint64_t pk = ((uint64_t)__float_as_uint(s) << 8) | (uint32_t)(79 - c);
            m = m > pk ? m : pk;
        }
        best = __uint_as_float((uint32_t)(m >> 8));
        bc = 79 - (int)(m & 0xFFu);
    }

    float so = sigmoidf_(ob[(size_t)n * HW + q]);
    float sc = __fmul_rn(best, so);
    float masked = (sc >= SCORE_THRF) ? sc : -1.0f;
    uint32_t u = __float_as_uint(masked);
    uint32_t ord = (u & 0x80000000u) ? ~u : (u | 0x80000000u);
    uint32_t dk = ~ord;                      // descending (valid => top bit 0)
    keys[a] = ((uint64_t)dk << 32) | (uint32_t)((p << 8) | bc);
}

// ---------------- Kernel 2: counting-sort top-1000 keys ----------------
__global__ __launch_bounds__(1024) void k_select(
    const uint64_t* __restrict__ keys,
    uint64_t* __restrict__ skeys, int* __restrict__ nvalid)
{
    __shared__ uint32_t hist[NB];
    __shared__ uint32_t base[NB];
    __shared__ uint32_t fill[NB];
    __shared__ uint64_t grouped[CAND_N];
    __shared__ uint64_t cand[CAND_N];
    __shared__ int      s_misc[2];

    int n = blockIdx.x, tid = threadIdx.x;

    if (tid < NB) { hist[tid] = 0; fill[tid] = 0; }
    for (int t = tid; t < CAND_N; t += 1024) cand[t] = ~0ull;
    __syncthreads();

    #pragma unroll
    for (int it = 0; it < 9; ++it) {
        int t = tid + it * 1024;
        if (t < P_TOT) {
            uint64_t k = keys[(size_t)n * P_TOT + t];
            uint32_t dk = (uint32_t)(k >> 32);
            if (!(dk & 0x80000000u)) atomicAdd(&hist[(dk >> 17) - BINBASE], 1u);
        }
    }
    __syncthreads();

    if (tid < 64) {
        uint32_t c[8]; uint32_t s = 0;
        #pragma unroll
        for (int i = 0; i < 8; ++i) { c[i] = hist[tid * 8 + i]; s += c[i]; }
        uint32_t inc = s;
        #pragma unroll
        for (int o = 1; o < 64; o <<= 1) {
            uint32_t v = __shfl_up(inc, o);
            if (tid >= o) inc += v;
        }
        uint32_t excl = inc - s;
        uint32_t b = excl;
        #pragma unroll
        for (int i = 0; i < 8; ++i) { base[tid * 8 + i] = b; b += c[i]; }
        uint32_t total = __shfl(inc, 63);
        uint32_t target = total < (uint32_t)NMS_PRE ? total : (uint32_t)NMS_PRE;
        uint32_t cum = excl; int found = 0x7fffffff;
        #pragma unroll
        for (int i = 0; i < 8; ++i) {
            cum += c[i];
            if (found == 0x7fffffff && cum >= target && target > 0) found = tid * 8 + i;
        }
        #pragma unroll
        for (int o = 32; o > 0; o >>= 1) { int f = __shfl_xor(found, o); found = f < found ? f : found; }
        if (tid == 0) { s_misc[0] = (total > 0) ? found : -1; s_misc[1] = (int)target; }
    }
    __syncthreads();
    int Bcut = s_misc[0];

    #pragma unroll
    for (int it = 0; it < 9; ++it) {
        int t = tid + it * 1024;
        if (t < P_TOT) {
            uint64_t k = keys[(size_t)n * P_TOT + t];
            uint32_t dk = (uint32_t)(k >> 32);
            if (!(dk & 0x80000000u)) {
                int bin = (int)((dk >> 17) - BINBASE);
                if (bin <= Bcut) {
                    uint32_t pos = base[bin] + atomicAdd(&fill[bin], 1u);
                    if (pos < CAND_N) grouped[pos] = k;
                }
            }
        }
    }
    __syncthreads();

    int ccnt = 0;
    if (Bcut >= 0) {
        uint32_t cc = base[Bcut] + hist[Bcut];
        ccnt = cc < (uint32_t)CAND_N ? (int)cc : CAND_N;
    }
    for (int s = tid; s < ccnt; s += 1024) {
        uint64_t k = grouped[s];
        uint32_t dk = (uint32_t)(k >> 32);
        int bin = (int)((dk >> 17) - BINBASE);
        uint32_t b0 = base[bin];
        uint32_t e0 = b0 + hist[bin]; if (e0 > (uint32_t)CAND_N) e0 = CAND_N;
        uint32_t r = b0;
        for (uint32_t t = b0; t < e0; ++t) r += (grouped[t] < k) ? 1u : 0u;
        if (r < (uint32_t)CAND_N) cand[r] = k;
    }
    __syncthreads();

    if (tid < NMS_PRE) skeys[n * NMS_PRE + tid] = cand[tid];
    if (tid == 0) nvalid[n] = s_misc[1];
}

// ---------------- Kernel 3: decode + gmax + greedy NMS + output ----------------
__global__ __launch_bounds__(256) void k_nms(
    const uint64_t* __restrict__ skeys, const int* __restrict__ nvalid,
    const float* __restrict__ reg0, const float* __restrict__ reg1, const float* __restrict__ reg2,
    float* __restrict__ out)
{
    __shared__ float4 s_obx[NMS_PRE];
    __shared__ float4 s_raw[NMS_PRE];
    __shared__ float2 s_sl[NMS_PRE];
    __shared__ float  s_oar[NMS_PRE];
    __shared__ float  fsh[4];
    __shared__ int    kidx[MAXOUT];

    int n = blockIdx.x, tid = threadIdx.x;
    int lane = tid & 63, wv = tid >> 6;
    int V = nvalid[n];

    float4 bx4[4]; float lab4[4];
    float m = 0.f;
    #pragma unroll
    for (int it = 0; it < 4; ++it) {
        int t = tid + it * 256;
        float4 bx = make_float4(0.f, 0.f, 0.f, 0.f);
        float scm = -1.0f, labf = 0.f;
        if (t < NMS_PRE) {
            uint64_t key = skeys[n * NMS_PRE + t];
            uint32_t dk = (uint32_t)(key >> 32);
            if (!(dk & 0x80000000u)) {
                uint32_t low = (uint32_t)key;
                int lab = (int)(low & 0xFFu);
                int p   = (int)(low >> 8);
                uint32_t ord = ~dk;
                scm = __uint_as_float(ord ^ 0x80000000u);

                const float* rg; int HW, q, W; float s;
                if (p < 6400)      { rg = reg0; HW = 6400; q = p;        W = 80; s = 8.f; }
                else if (p < 8000) { rg = reg1; HW = 1600; q = p - 6400; W = 40; s = 16.f; }
                else               { rg = reg2; HW = 400;  q = p - 8000; W = 20; s = 32.f; }

                float px = (float)(q % W) * s;
                float py = (float)(q / W) * s;
                const float* rb = rg + (size_t)n * 4 * HW + q;
                float dx = rb[0], dy = rb[HW], dw = rb[2 * HW], dh = rb[3 * HW];
                float cx = __fadd_rn(__fmul_rn(dx, s), px);
                float cy = __fadd_rn(__fmul_rn(dy, s), py);
                float hw = __fmul_rn(__fmul_rn(expf(dw), s), 0.5f);
                float hh = __fmul_rn(__fmul_rn(expf(dh), s), 0.5f);
                bx.x = __fsub_rn(cx, hw); bx.y = __fsub_rn(cy, hh);
                bx.z = __fadd_rn(cx, hw); bx.w = __fadd_rn(cy, hh);
                labf = (float)lab;
                m = fmaxf(m, fmaxf(fmaxf(fabsf(bx.x), fabsf(bx.y)), fmaxf(fabsf(bx.z), fabsf(bx.w))));
            }
            s_raw[t] = bx;
            s_sl[t]  = make_float2(scm, labf);
        }
        bx4[it] = bx; lab4[it] = labf;
    }

    #pragma unroll
    for (int o = 32; o > 0; o >>= 1) m = fmaxf(m, __shfl_xor(m, o));
    if (lane == 0) fsh[wv] = m;
    __syncthreads();
    float gmax = fmaxf(fmaxf(fsh[0], fsh[1]), fmaxf(fsh[2], fsh[3]));

    #pragma unroll
    for (int it = 0; it < 4; ++it) {
        int t = tid + it * 256;
        if (t < NMS_PRE) {
            float off = __fmul_rn(lab4[it], __fadd_rn(gmax, 1.0f));
            float x1 = __fadd_rn(bx4[it].x, off), y1 = __fadd_rn(bx4[it].y, off);
            float x2 = __fadd_rn(bx4[it].z, off), y2 = __fadd_rn(bx4[it].w, off);
            s_obx[t] = make_float4(x1, y1, x2, y2);
            s_oar[t] = __fmul_rn(__fsub_rn(x2, x1), __fsub_rn(y2, y1));
        }
    }
    __syncthreads();
    if (tid >= 64) return;

    int count = 0;
    float k1x1 = 0.f, k1y1 = 0.f, k1x2 = 0.f, k1y2 = 0.f, k1a = 0.f;
    float k2x1 = 0.f, k2y1 = 0.f, k2x2 = 0.f, k2y2 = 0.f, k2a = 0.f;

    float4 nb = s_obx[0]; float na = s_oar[0];
    for (int i = 0; i < V && count < MAXOUT; ++i) {
        float4 cb = nb; float ca = na;
        int ip = (i + 1 < V) ? i + 1 : i;
        nb = s_obx[ip]; na = s_oar[ip];

        bool sup = false;
        int c1 = count < 64 ? count : 64;
        if (lane < c1) {
            float ltx = fmaxf(k1x1, cb.x), lty = fmaxf(k1y1, cb.y);
            float rbx = fminf(k1x2, cb.z), rby = fminf(k1y2, cb.w);
            float w = fmaxf(__fsub_rn(rbx, ltx), 0.f);
            float h = fmaxf(__fsub_rn(rby, lty), 0.f);
            float inter = __fmul_rn(w, h);
            float denom = __fadd_rn(__fsub_rn(__fadd_rn(k1a, ca), inter), 1e-9f);
            sup = (inter / denom > NMS_THRF);
        }
        if (count > 64 && lane < count - 64) {
            float ltx = fmaxf(k2x1, cb.x), lty = fmaxf(k2y1, cb.y);
            float rbx = fminf(k2x2, cb.z), rby = fminf(k2y2, cb.w);
            float w = fmaxf(__fsub_rn(rbx, ltx), 0.f);
            float h = fmaxf(__fsub_rn(rby, lty), 0.f);
            float inter = __fmul_rn(w, h);
            float denom = __fadd_rn(__fsub_rn(__fadd_rn(k2a, ca), inter), 1e-9f);
            sup = sup || (inter / denom > NMS_THRF);
        }
        if (__ballot(sup) == 0ull) {
            if (lane == count)      { k1x1 = cb.x; k1y1 = cb.y; k1x2 = cb.z; k1y2 = cb.w; k1a = ca; }
            if (lane + 64 == count) { k2x1 = cb.x; k2y1 = cb.y; k2x2 = cb.z; k2y2 = cb.w; k2a = ca; }
            if (lane == 0) kidx[count] = i;
            ++count;
        }
    }

    float* ob = out;
    float* os = out + N_IMG * MAXOUT * 4;
    float* ol = os + N_IMG * MAXOUT;
    for (int mi = lane; mi < MAXOUT; mi += 64) {
        int o4 = (n * MAXOUT + mi) * 4;
        if (mi < count) {
            int i = kidx[mi];
            float4 b  = s_raw[i];
            float2 sl = s_sl[i];
            ob[o4 + 0] = b.x; ob[o4 + 1] = b.y; ob[o4 + 2] = b.z; ob[o4 + 3] = b.w;
            os[n * MAXOUT + mi] = sl.x;
            ol[n * MAXOUT + mi] = sl.y;
        } else {
            ob[o4 + 0] = 0.f; ob[o4 + 1] = 0.f; ob[o4 + 2] = 0.f; ob[o4 + 3] = 0.f;
            os[n * MAXOUT + mi] = 0.f;
            ol[n * MAXOUT + mi] = -1.f;
        }
    }
}

extern "C" void kernel_launch(void* const* d_in, const int* in_sizes, int n_in,
                              void* d_out, int out_size, void* d_ws, size_t ws_size,
                              hipStream_t stream)
{
    const float* cls0 = (const float*)d_in[0];
    const float* cls1 = (const float*)d_in[1];
    const float* cls2 = (const float*)d_in[2];
    const float* reg0 = (const float*)d_in[3];
    const float* reg1 = (const float*)d_in[4];
    const float* reg2 = (const float*)d_in[5];
    const float* obj0 = (const float*)d_in[6];
    const float* obj1 = (const float*)d_in[7];
    const float* obj2 = (const float*)d_in[8];

    uint64_t*   keys   = (uint64_t*)d_ws;                                  // 2.1 MB
    uint64_t*   skeys  = (uint64_t*)((char*)d_ws + (4u << 20));            // 256 KB
    int*        nvalid = (int*)((char*)d_ws + (4u << 20) + (512u << 10));
    ulonglong2* part   = (ulonglong2*)((char*)d_ws + (8u << 20));          // 21.5 MB
    float* out = (float*)d_out;

    k_pmax<<<N_IMG * TILES * CHUNKS, 1024, 0, stream>>>(cls0, cls1, cls2, part);
    k_merge<<<(N_IMG * P_TOT + 255) / 256, 256, 0, stream>>>(
        part, cls0, cls1, cls2, obj0, obj1, obj2, keys);
    k_select<<<N_IMG, 1024, 0, stream>>>(keys, skeys, nvalid);
    k_nms<<<N_IMG, 256, 0, stream>>>(skeys, nvalid, reg0, reg1, reg2, out);
}

// Round 14
// 67.772 us; speedup vs baseline: 1.5505x; 1.5505x over previous
//
#include <hip/hip_runtime.h>
#include <stdint.h>

#define N_IMG 32
#define P_TOT 8400
#define NCLS 80
#define NMS_PRE 1000
#define MAXOUT 100
#define SCORE_THRF 0.01f
#define NMS_THRF 0.65f
#define CAND_N 2048
#define NB 512          // histogram bins over dk>>17
#define BINBASE 8192    // valid masked scores [0.01,1.0] -> dk>>17 in [8255,8686]
#define TIE_EPS 0.05f   // sigmoid float-rounding tie window (validated R9/R10/R12, absmax 0)

// Level layout: p in [0,6400): 80x80 s=8 ; [6400,8000): 40x40 s=16 ; [8000,8400): 20x20 s=32

__device__ __forceinline__ float sigmoidf_(float x) { return 1.0f / (1.0f + expf(-x)); }

// ---------------- Kernel 1: scores -> sort keys (R12, unchanged) ----------------
__global__ __launch_bounds__(256) void k_score(
    const float* __restrict__ cls0, const float* __restrict__ cls1, const float* __restrict__ cls2,
    const float* __restrict__ obj0, const float* __restrict__ obj1, const float* __restrict__ obj2,
    uint64_t* __restrict__ keys)
{
    __shared__ float    pml[4][64];    // per-wave partial max logit
    __shared__ uint64_t part[4][64];   // per-wave partial packed sigmoid-argmax
    int lane = threadIdx.x & 63, wid = threadIdx.x >> 6;
    int a = blockIdx.x * 64 + lane;          // global anchor id, < 268800 exactly
    int n = a / P_TOT;
    int p = a - n * P_TOT;

    const float* cl; const float* ob; int HW, q;
    if (p < 6400)      { cl = cls0; ob = obj0; HW = 6400; q = p; }
    else if (p < 8000) { cl = cls1; ob = obj1; HW = 1600; q = p - 6400; }
    else               { cl = cls2; ob = obj2; HW = 400;  q = p - 8000; }

    const float* cbase = cl + (size_t)n * NCLS * HW + q;
    int c0 = wid * 20;

    float lg[20];
    #pragma unroll
    for (int i = 0; i < 20; ++i)
        lg[i] = cbase[(size_t)(c0 + i) * HW];
    __builtin_amdgcn_sched_group_barrier(0x20, 20, 0);   // 20 VMEM reads back-to-back

    float a0 = fmaxf(lg[0], lg[1]),  a1 = fmaxf(lg[2], lg[3]);
    float a2 = fmaxf(lg[4], lg[5]),  a3 = fmaxf(lg[6], lg[7]);
    float a4 = fmaxf(lg[8], lg[9]),  a5 = fmaxf(lg[10], lg[11]);
    float a6 = fmaxf(lg[12], lg[13]), a7 = fmaxf(lg[14], lg[15]);
    float a8 = fmaxf(lg[16], lg[17]), a9 = fmaxf(lg[18], lg[19]);
    float b0 = fmaxf(a0, a1), b1 = fmaxf(a2, a3), b2 = fmaxf(a4, a5);
    float b3 = fmaxf(a6, a7), b4 = fmaxf(a8, a9);
    float lmax = fmaxf(fmaxf(fmaxf(b0, b1), fmaxf(b2, b3)), b4);
    pml[wid][lane] = lmax;
    __syncthreads();

    float gmaxl = fmaxf(fmaxf(pml[0][lane], pml[1][lane]),
                        fmaxf(pml[2][lane], pml[3][lane]));
    float thr = gmaxl - TIE_EPS;
    uint64_t m = 0;
    #pragma unroll
    for (int i = 0; i < 20; ++i) {
        if (lg[i] >= thr) {
            float s = sigmoidf_(lg[i]);
            uint64_t pk = ((uint64_t)__float_as_uint(s) << 8) | (uint32_t)(79 - (c0 + i));
            m = m > pk ? m : pk;    // equal sig -> lower class wins (= jnp.argmax)
        }
    }
    part[wid][lane] = m;
    __syncthreads();

    if (wid == 0) {
        uint64_t m0 = part[0][lane], m1 = part[1][lane];
        uint64_t m2 = part[2][lane], m3 = part[3][lane];
        uint64_t ma = m0 > m1 ? m0 : m1, mb = m2 > m3 ? m2 : m3;
        uint64_t mm = ma > mb ? ma : mb;
        float best = __uint_as_float((uint32_t)(mm >> 8));   // = max_c sigmoid(cls_c), exact
        int bc = 79 - (int)(mm & 0xFFu);

        float so = sigmoidf_(ob[(size_t)n * HW + q]);
        float sc = __fmul_rn(best, so);
        float masked = (sc >= SCORE_THRF) ? sc : -1.0f;
        uint32_t u = __float_as_uint(masked);
        uint32_t ord = (u & 0x80000000u) ? ~u : (u | 0x80000000u);
        uint32_t dk = ~ord;                  // descending (valid => top bit 0)
        keys[a] = ((uint64_t)dk << 32) | (uint32_t)((p << 8) | bc);
    }
}

// ---------------- Kernel 2: counting-sort select + decode + NMS + output (fused) ----------------
// LDS overlay: cand[2048] fixed; region B holds hist/base/fill/grouped during select,
// then obx/oar/raw/sl for NMS (grouped dead after ranking).
__global__ __launch_bounds__(1024) void k_selnms(
    const uint64_t* __restrict__ keys,
    const float* __restrict__ reg0, const float* __restrict__ reg1, const float* __restrict__ reg2,
    float* __restrict__ out)
{
    __shared__ __align__(16) char big[60416];
    __shared__ int   s_misc[2];
    __shared__ float fsh[17];
    __shared__ int   kidx[MAXOUT];

    uint64_t* cand    = (uint64_t*)big;                 // [2048]  (16384 B), whole kernel
    // select-phase overlays (big+16384 ..):
    uint32_t* hist    = (uint32_t*)(big + 16384);       // [512]
    uint32_t* base    = (uint32_t*)(big + 18432);       // [512]
    uint32_t* fill    = (uint32_t*)(big + 20480);       // [512]
    uint64_t* grouped = (uint64_t*)(big + 22528);       // [2048] (ends 38912)
    // nms-phase overlays (same region, after ranking):
    float4* s_obx = (float4*)(big + 16384);             // [1000] (16000)
    float*  s_oar = (float*) (big + 32384);             // [1000] ( 4000)
    float4* s_raw = (float4*)(big + 36384);             // [1000] (16000)
    float2* s_sl  = (float2*)(big + 52384);             // [1000] ( 8000) -> ends 60384

    int n = blockIdx.x, tid = threadIdx.x;

    if (tid < NB) { hist[tid] = 0; fill[tid] = 0; }
    for (int t = tid; t < CAND_N; t += 1024) cand[t] = ~0ull;
    __syncthreads();

    // pass 1: histogram valid keys
    #pragma unroll
    for (int it = 0; it < 9; ++it) {
        int t = tid + it * 1024;
        if (t < P_TOT) {
            uint64_t k = keys[(size_t)n * P_TOT + t];
            uint32_t dk = (uint32_t)(k >> 32);
            if (!(dk & 0x80000000u)) atomicAdd(&hist[(dk >> 17) - BINBASE], 1u);
        }
    }
    __syncthreads();

    // wave-0 prefix over 512 bins: per-bin exclusive base, total, cutoff bin
    if (tid < 64) {
        uint32_t c[8]; uint32_t s = 0;
        #pragma unroll
        for (int i = 0; i < 8; ++i) { c[i] = hist[tid * 8 + i]; s += c[i]; }
        uint32_t inc = s;
        #pragma unroll
        for (int o = 1; o < 64; o <<= 1) {
            uint32_t v = __shfl_up(inc, o);
            if (tid >= o) inc += v;
        }
        uint32_t excl = inc - s;
        uint32_t b = excl;
        #pragma unroll
        for (int i = 0; i < 8; ++i) { base[tid * 8 + i] = b; b += c[i]; }
        uint32_t total = __shfl(inc, 63);
        uint32_t target = total < (uint32_t)NMS_PRE ? total : (uint32_t)NMS_PRE;
        uint32_t cum = excl; int found = 0x7fffffff;
        #pragma unroll
        for (int i = 0; i < 8; ++i) {
            cum += c[i];
            if (found == 0x7fffffff && cum >= target && target > 0) found = tid * 8 + i;
        }
        #pragma unroll
        for (int o = 32; o > 0; o >>= 1) { int f = __shfl_xor(found, o); found = f < found ? f : found; }
        if (tid == 0) { s_misc[0] = (total > 0) ? found : -1; s_misc[1] = (int)target; }
    }
    __syncthreads();
    int Bcut = s_misc[0];

    // pass 2: scatter candidates (bins <= Bcut) into bin-grouped order (keys L2-warm)
    #pragma unroll
    for (int it = 0; it < 9; ++it) {
        int t = tid + it * 1024;
        if (t < P_TOT) {
            uint64_t k = keys[(size_t)n * P_TOT + t];
            uint32_t dk = (uint32_t)(k >> 32);
            if (!(dk & 0x80000000u)) {
                int bin = (int)((dk >> 17) - BINBASE);
                if (bin <= Bcut) {
                    uint32_t pos = base[bin] + atomicAdd(&fill[bin], 1u);
                    if (pos < CAND_N) grouped[pos] = k;
                }
            }
        }
    }
    __syncthreads();

    // exact rank within bin (keys unique -> total order identical to full sort)
    int ccnt = 0;
    if (Bcut >= 0) {
        uint32_t cc = base[Bcut] + hist[Bcut];
        ccnt = cc < (uint32_t)CAND_N ? (int)cc : CAND_N;
    }
    for (int s = tid; s < ccnt; s += 1024) {
        uint64_t k = grouped[s];
        uint32_t dk = (uint32_t)(k >> 32);
        int bin = (int)((dk >> 17) - BINBASE);
        uint32_t b0 = base[bin];
        uint32_t e0 = b0 + hist[bin]; if (e0 > (uint32_t)CAND_N) e0 = CAND_N;
        uint32_t r = b0;
        for (uint32_t t = b0; t < e0; ++t) r += (grouped[t] < k) ? 1u : 0u;
        if (r < (uint32_t)CAND_N) cand[r] = k;
    }
    int V = s_misc[1];
    __syncthreads();          // ranking done; hist/base/fill/grouped dead below

    // decode top-1000 from cand (LDS) exactly like reference; 1 anchor per thread
    float4 bx = make_float4(0.f, 0.f, 0.f, 0.f);
    float scm = -1.0f, labf = 0.f, m = 0.f;
    if (tid < NMS_PRE) {
        uint64_t key = cand[tid];
        uint32_t dk = (uint32_t)(key >> 32);
        if (!(dk & 0x80000000u)) {
            uint32_t low = (uint32_t)key;
            int lab = (int)(low & 0xFFu);
            int p   = (int)(low >> 8);
            uint32_t ord = ~dk;
            scm = __uint_as_float(ord ^ 0x80000000u);   // valid => positive float

            const float* rg; int HW, q, W; float s;
            if (p < 6400)      { rg = reg0; HW = 6400; q = p;        W = 80; s = 8.f; }
            else if (p < 8000) { rg = reg1; HW = 1600; q = p - 6400; W = 40; s = 16.f; }
            else               { rg = reg2; HW = 400;  q = p - 8000; W = 20; s = 32.f; }

            float px = (float)(q % W) * s;   // exact
            float py = (float)(q / W) * s;   // exact
            const float* rb = rg + (size_t)n * 4 * HW + q;
            float dx = rb[0], dy = rb[HW], dw = rb[2 * HW], dh = rb[3 * HW];
            float cx = __fadd_rn(__fmul_rn(dx, s), px);
            float cy = __fadd_rn(__fmul_rn(dy, s), py);
            float hw = __fmul_rn(__fmul_rn(expf(dw), s), 0.5f);
            float hh = __fmul_rn(__fmul_rn(expf(dh), s), 0.5f);
            bx.x = __fsub_rn(cx, hw); bx.y = __fsub_rn(cy, hh);
            bx.z = __fadd_rn(cx, hw); bx.w = __fadd_rn(cy, hh);
            labf = (float)lab;
            m = fmaxf(fmaxf(fabsf(bx.x), fabsf(bx.y)), fmaxf(fabsf(bx.z), fabsf(bx.w)));
        }
    }

    // gmax = max|b| over the 1000 gathered boxes (16-wave reduce)
    #pragma unroll
    for (int o = 32; o > 0; o >>= 1) m = fmaxf(m, __shfl_xor(m, o));
    if ((tid & 63) == 0) fsh[tid >> 6] = m;
    __syncthreads();
    if (tid == 0) {
        float g = fsh[0];
        #pragma unroll
        for (int w = 1; w < 16; ++w) g = fmaxf(g, fsh[w]);
        fsh[16] = g;
    }
    __syncthreads();
    float gmax = fsh[16];

    // stage NMS arrays (overlays dead select region; cand region untouched until here)
    if (tid < NMS_PRE) {
        float off = __fmul_rn(labf, __fadd_rn(gmax, 1.0f)); // lab * (max|b| + 1)
        float x1 = __fadd_rn(bx.x, off), y1 = __fadd_rn(bx.y, off);
        float x2 = __fadd_rn(bx.z, off), y2 = __fadd_rn(bx.w, off);
        s_obx[tid] = make_float4(x1, y1, x2, y2);
        s_oar[tid] = __fmul_rn(__fsub_rn(x2, x1), __fsub_rn(y2, y1));
        s_raw[tid] = bx;
        s_sl[tid]  = make_float2(scm, labf);
    }
    __syncthreads();
    if (tid >= 64) return;      // wave 0 finishes alone

    // ---- greedy NMS: lanes = kept boxes; candidates serial with LDS-broadcast prefetch ----
    int lane = tid;
    int count = 0;
    float k1x1 = 0.f, k1y1 = 0.f, k1x2 = 0.f, k1y2 = 0.f, k1a = 0.f;  // kept[lane]
    float k2x1 = 0.f, k2y1 = 0.f, k2x2 = 0.f, k2y2 = 0.f, k2a = 0.f;  // kept[lane+64]

    float4 nb = s_obx[0]; float na = s_oar[0];
    for (int i = 0; i < V && count < MAXOUT; ++i) {
        float4 cb = nb; float ca = na;
        int ip = (i + 1 < V) ? i + 1 : i;
        nb = s_obx[ip]; na = s_oar[ip];     // prefetch next candidate (indep of decision)

        bool sup = false;
        int c1 = count < 64 ? count : 64;
        if (lane < c1) {
            float ltx = fmaxf(k1x1, cb.x), lty = fmaxf(k1y1, cb.y);
            float rbx = fminf(k1x2, cb.z), rby = fminf(k1y2, cb.w);
            float w = fmaxf(__fsub_rn(rbx, ltx), 0.f);
            float h = fmaxf(__fsub_rn(rby, lty), 0.f);
            float inter = __fmul_rn(w, h);
            float denom = __fadd_rn(__fsub_rn(__fadd_rn(k1a, ca), inter), 1e-9f);
            sup = (inter / denom > NMS_THRF);
        }
        if (count > 64 && lane < count - 64) {
            float ltx = fmaxf(k2x1, cb.x), lty = fmaxf(k2y1, cb.y);
            float rbx = fminf(k2x2, cb.z), rby = fminf(k2y2, cb.w);
            float w = fmaxf(__fsub_rn(rbx, ltx), 0.f);
            float h = fmaxf(__fsub_rn(rby, lty), 0.f);
            float inter = __fmul_rn(w, h);
            float denom = __fadd_rn(__fsub_rn(__fadd_rn(k2a, ca), inter), 1e-9f);
            sup = sup || (inter / denom > NMS_THRF);
        }
        if (__ballot(sup) == 0ull) {
            if (lane == count)      { k1x1 = cb.x; k1y1 = cb.y; k1x2 = cb.z; k1y2 = cb.w; k1a = ca; }
            if (lane + 64 == count) { k2x1 = cb.x; k2y1 = cb.y; k2x2 = cb.z; k2y2 = cb.w; k2a = ca; }
            if (lane == 0) kidx[count] = i;
            ++count;
        }
    }

    float* ob = out;                          // [32*100*4]
    float* os = out + N_IMG * MAXOUT * 4;     // [32*100]
    float* ol = os + N_IMG * MAXOUT;          // [32*100] labels as float
    for (int mi = lane; mi < MAXOUT; mi += 64) {
        int o4 = (n * MAXOUT + mi) * 4;
        if (mi < count) {
            int i = kidx[mi];
            float4 b  = s_raw[i];
            float2 sl = s_sl[i];
            ob[o4 + 0] = b.x; ob[o4 + 1] = b.y; ob[o4 + 2] = b.z; ob[o4 + 3] = b.w;
            os[n * MAXOUT + mi] = sl.x;
            ol[n * MAXOUT + mi] = sl.y;
        } else {
            ob[o4 + 0] = 0.f; ob[o4 + 1] = 0.f; ob[o4 + 2] = 0.f; ob[o4 + 3] = 0.f;
            os[n * MAXOUT + mi] = 0.f;
            ol[n * MAXOUT + mi] = -1.f;
        }
    }
}

extern "C" void kernel_launch(void* const* d_in, const int* in_sizes, int n_in,
                              void* d_out, int out_size, void* d_ws, size_t ws_size,
                              hipStream_t stream)
{
    const float* cls0 = (const float*)d_in[0];
    const float* cls1 = (const float*)d_in[1];
    const float* cls2 = (const float*)d_in[2];
    const float* reg0 = (const float*)d_in[3];
    const float* reg1 = (const float*)d_in[4];
    const float* reg2 = (const float*)d_in[5];
    const float* obj0 = (const float*)d_in[6];
    const float* obj1 = (const float*)d_in[7];
    const float* obj2 = (const float*)d_in[8];

    uint64_t* keys = (uint64_t*)d_ws;     // 32*8400*8 B = 2.1 MB
    float* out = (float*)d_out;

    k_score<<<(N_IMG * P_TOT) / 64, 256, 0, stream>>>(
        cls0, cls1, cls2, obj0, obj1, obj2, keys);
    k_selnms<<<N_IMG, 1024, 0, stream>>>(keys, reg0, reg1, reg2, out);
}